// Round 2
// baseline (1530.401 us; speedup 1.0000x reference)
//
#include <hip/hip_runtime.h>

// Instant-NGP 2D hashgrid (L=16, T=2^20, F=2, N_MIN=16, b=2) + MLP 32->128->128->3.
// Fused single kernel: encode feeds MFMA B-fragments directly in registers.
// R2: removed per-iteration __syncthreads (hbuf is per-wave; w2T read-only
// after init) + ping-pong software pipeline (issue tile t+1 gathers before
// consuming tile t) so ~600-cycle L3 gather latency overlaps MFMA/LDS work.
//
// GEMM formulation: h^T = W^T x^T  (rows m = neurons, cols n = points).
//   mfma_f32_16x16x32_bf16 layouts (HW-verified per guide):
//     A[m][k]: m = lane&15, k = (lane>>4)*8 + j   (8 bf16 / lane)
//     B[k][n]: n = lane&15, k = (lane>>4)*8 + j
//     D[m][n]: n = lane&15, m = (lane>>4)*4 + r   (4 f32 / lane)
// Lane (quad, lo) encodes point lo at levels 4*quad .. 4*quad+3 == features
// k = quad*8 .. quad*8+7  ->  exactly its layer-1 B-fragment. No shuffle.

#define T_SIZE  (1u << 20)
#define HASH_Y  2654435761u

typedef __bf16 bf16x8 __attribute__((ext_vector_type(8)));
typedef float f32x4 __attribute__((ext_vector_type(4)));
typedef unsigned short u16x8 __attribute__((ext_vector_type(8)));
typedef unsigned short u16x4 __attribute__((ext_vector_type(4)));

static __device__ __forceinline__ unsigned short f2bf(float f) {
    union { float f; unsigned u; } v; v.f = f;
    unsigned u = v.u;
    u += 0x7fffu + ((u >> 16) & 1u);   // round-to-nearest-even
    return (unsigned short)(u >> 16);
}

static __device__ __forceinline__ f32x4 mfma16(u16x8 a, u16x8 b, f32x4 c) {
    return __builtin_amdgcn_mfma_f32_16x16x32_bf16(
        __builtin_bit_cast(bf16x8, a), __builtin_bit_cast(bf16x8, b), c, 0, 0, 0);
}

// Per-lane in-flight gather state for one 16-point tile (4 levels x 4 corners).
struct Pref {
    float2 f[16];
    float wx[4], wy[4];
};

// Issue the 16 table gathers for point `pt`, levels 4*quad..4*quad+3.
// Loads land in P.f; vmcnt waits are deferred to first use (consume step).
static __device__ __forceinline__ void issue_gathers(
    Pref& P, const float2* __restrict__ uv2, const float2* __restrict__ t2base,
    int pt, int quad)
{
    float2 p = uv2[pt];
#pragma unroll
    for (int i = 0; i < 4; ++i) {
        int lvl = (quad << 2) + i;
        unsigned res = 16u << lvl;
        float px = p.x * (float)res, py = p.y * (float)res;
        float fx = floorf(px), fy = floorf(py);
        P.wx[i] = px - fx;
        P.wy[i] = py - fy;
        unsigned cx = (unsigned)fx, cy = (unsigned)fy;
        unsigned rp1 = res + 1u;
        unsigned hy0 = cy * HASH_Y, hy1 = (cy + 1u) * HASH_Y;
        const unsigned mask = T_SIZE - 1u;
        bool dense = lvl < 6;                  // (res+1)^2 <= T  <=>  lvl <= 5
        unsigned i00 = dense ? (cx + cy * rp1)              : ((cx ^ hy0) & mask);
        unsigned i01 = dense ? (cx + (cy + 1u) * rp1)       : ((cx ^ hy1) & mask);
        unsigned i10 = dense ? (cx + 1u + cy * rp1)         : (((cx + 1u) ^ hy0) & mask);
        unsigned i11 = dense ? (cx + 1u + (cy + 1u) * rp1)  : (((cx + 1u) ^ hy1) & mask);
        const float2* t2 = t2base + (size_t)lvl * T_SIZE;
        P.f[4 * i + 0] = t2[i00];
        P.f[4 * i + 1] = t2[i01];
        P.f[4 * i + 2] = t2[i10];
        P.f[4 * i + 3] = t2[i11];
    }
}

// Consume one tile: bilinear interp -> layer1 -> LDS -> layer2 -> LDS -> layer3 -> out.
static __device__ __forceinline__ void mlp_tile(
    const Pref& P, int pt, int quad, int lanelo,
    unsigned short* __restrict__ hp, const unsigned short* __restrict__ w2T,
    const u16x8* __restrict__ a1, const u16x8* __restrict__ a3,
    const float* __restrict__ b1s, const float* __restrict__ b2s,
    const float* __restrict__ b3, float* __restrict__ out)
{
    // ---- bilinear interp (waits on this tile's gathers here) ----
    u16x8 xb;
#pragma unroll
    for (int i = 0; i < 4; ++i) {
        float wx = P.wx[i], wy = P.wy[i];
        float w00 = (1.f - wx) * (1.f - wy);
        float w01 = (1.f - wx) * wy;
        float w10 = wx * (1.f - wy);
        float w11 = wx * wy;
        float2 f00 = P.f[4 * i + 0], f01 = P.f[4 * i + 1];
        float2 f10 = P.f[4 * i + 2], f11 = P.f[4 * i + 3];
        float g0 = w00 * f00.x + w01 * f01.x + w10 * f10.x + w11 * f11.x;
        float g1 = w00 * f00.y + w01 * f01.y + w10 * f10.y + w11 * f11.y;
        xb[2 * i]     = f2bf(g0);
        xb[2 * i + 1] = f2bf(g1);
    }
    // ---- layer 1: 8 MFMAs, K=32 ----
    f32x4 z = {0.f, 0.f, 0.f, 0.f};
    f32x4 d[8];
#pragma unroll
    for (int mt = 0; mt < 8; ++mt) d[mt] = mfma16(a1[mt], xb, z);
#pragma unroll
    for (int mt = 0; mt < 8; ++mt) {
        u16x4 pk;
#pragma unroll
        for (int r = 0; r < 4; ++r) {
            float hv = d[mt][r] + b1s[mt * 16 + quad * 4 + r];
            pk[r] = f2bf(fmaxf(hv, 0.f));
        }
        *(u16x4*)(hp + mt * 16 + quad * 4) = pk;
    }
    // ---- layer 2: K=128 in 4 steps x 8 m-tiles (wave-internal LDS, DS in-order) ----
    f32x4 e[8];
#pragma unroll
    for (int mt = 0; mt < 8; ++mt) e[mt] = z;
#pragma unroll
    for (int ks = 0; ks < 4; ++ks) {
        u16x8 bb = *(const u16x8*)(hp + ks * 32 + quad * 8);
#pragma unroll
        for (int mt = 0; mt < 8; ++mt) {
            u16x8 aa = *(const u16x8*)(w2T + (mt * 16 + lanelo) * 136 + ks * 32 + quad * 8);
            e[mt] = mfma16(aa, bb, e[mt]);
        }
    }
#pragma unroll
    for (int mt = 0; mt < 8; ++mt) {
        u16x4 pk;
#pragma unroll
        for (int r = 0; r < 4; ++r) {
            float hv = e[mt][r] + b2s[mt * 16 + quad * 4 + r];
            pk[r] = f2bf(fmaxf(hv, 0.f));
        }
        *(u16x4*)(hp + mt * 16 + quad * 4) = pk;
    }
    // ---- layer 3: 4 MFMAs, rows 0..2 = RGB logits ----
    f32x4 o3 = z;
#pragma unroll
    for (int ks = 0; ks < 4; ++ks) {
        u16x8 bb = *(const u16x8*)(hp + ks * 32 + quad * 8);
        o3 = mfma16(a3[ks], bb, o3);
    }
    if (quad == 0) {   // D rows 0..2 live in quad 0, r=0..2
        float* op = out + (size_t)pt * 3;
#pragma unroll
        for (int r = 0; r < 3; ++r) {
            float lv = o3[r] + b3[r];
            op[r] = 1.f / (1.f + expf(-lv));
        }
    }
}

// LDS: w2T[out 128][in 136 pad] bf16 (34816 B) + h[4 waves][16 pts][136 pad]
// (17408 B) + biases (1024 B) = 53248 B -> 3 blocks/CU (LDS-bound).
__global__ __launch_bounds__(256, 3)
void fused_ngp_mlp(const float* __restrict__ uv, const float* __restrict__ tables,
                   const float* __restrict__ w1, const float* __restrict__ b1,
                   const float* __restrict__ w2, const float* __restrict__ b2,
                   const float* __restrict__ w3, const float* __restrict__ b3,
                   float* __restrict__ out, int npts)
{
    __shared__ __align__(16) unsigned short w2T[128 * 136];
    __shared__ __align__(16) unsigned short hbuf[4 * 16 * 136];
    __shared__ float b1s[128], b2s[128];

    const int tid = threadIdx.x;
    for (int e2 = tid; e2 < 128 * 128; e2 += 256) {     // w2 is [in][out]; store w2T[out][in]
        int i = e2 >> 7, o = e2 & 127;
        w2T[o * 136 + i] = f2bf(w2[e2]);
    }
    if (tid < 128) { b1s[tid] = b1[tid]; b2s[tid] = b2[tid]; }
    __syncthreads();   // only barrier: w2T/bias init. hbuf is per-wave after this.

    const int lane = tid & 63;
    const int wv = tid >> 6;
    const int lanelo = lane & 15;
    const int quad = lane >> 4;

    // Register-resident A-fragments: layer 1 (w1^T [128x32]) and layer 3 (w3^T [3x128]).
    u16x8 a1[8];
#pragma unroll
    for (int mt = 0; mt < 8; ++mt)
#pragma unroll
        for (int j = 0; j < 8; ++j)
            a1[mt][j] = f2bf(w1[(quad * 8 + j) * 128 + mt * 16 + lanelo]);  // w1[k][m]

    u16x8 a3[4];
#pragma unroll
    for (int ks = 0; ks < 4; ++ks)
#pragma unroll
        for (int j = 0; j < 8; ++j) {
            int k = ks * 32 + quad * 8 + j;
            a3[ks][j] = (lanelo < 3) ? f2bf(w3[k * 3 + lanelo]) : (unsigned short)0;  // w3[k][m]
        }

    const int NT = npts >> 4;                 // 16-point tiles
    const int nwaves = gridDim.x * 4;
    const int gwave = blockIdx.x * 4 + wv;

    unsigned short* hp = hbuf + (wv * 16 + lanelo) * 136;   // this lane's point-row
    const float2* t2base = (const float2*)tables;
    const float2* uv2 = (const float2*)uv;

    // ---- ping-pong pipelined persistent loop (x2 unrolled, no reg copies) ----
    int tile = gwave;
    if (tile >= NT) return;
    Pref A, B;
    issue_gathers(A, uv2, t2base, (tile << 4) + lanelo, quad);
    for (;;) {
        int tB = tile + nwaves;
        if (tB < NT) {
            issue_gathers(B, uv2, t2base, (tB << 4) + lanelo, quad);
            mlp_tile(A, (tile << 4) + lanelo, quad, lanelo, hp, w2T, a1, a3, b1s, b2s, b3, out);
            int tA = tB + nwaves;
            if (tA < NT) {
                issue_gathers(A, uv2, t2base, (tA << 4) + lanelo, quad);
                mlp_tile(B, (tB << 4) + lanelo, quad, lanelo, hp, w2T, a1, a3, b1s, b2s, b3, out);
                tile = tA;
            } else {
                mlp_tile(B, (tB << 4) + lanelo, quad, lanelo, hp, w2T, a1, a3, b1s, b2s, b3, out);
                return;
            }
        } else {
            mlp_tile(A, (tile << 4) + lanelo, quad, lanelo, hp, w2T, a1, a3, b1s, b2s, b3, out);
            return;
        }
    }
}

extern "C" void kernel_launch(void* const* d_in, const int* in_sizes, int n_in,
                              void* d_out, int out_size, void* d_ws, size_t ws_size,
                              hipStream_t stream) {
    const float* uv     = (const float*)d_in[0];
    const float* tables = (const float*)d_in[1];
    const float* w1     = (const float*)d_in[2];
    const float* b1     = (const float*)d_in[3];
    const float* w2     = (const float*)d_in[4];
    const float* b2     = (const float*)d_in[5];
    const float* w3     = (const float*)d_in[6];
    const float* b3     = (const float*)d_in[7];
    float* out = (float*)d_out;
    int npts = in_sizes[0] / 2;          // uv is [N,2]
    // 2048 blocks x 4 waves = 8192 wave-slots; 65536 tiles -> 8 tiles/wave, exact.
    hipLaunchKernelGGL(fused_ngp_mlp, dim3(2048), dim3(256), 0, stream,
                       uv, tables, w1, b1, w2, b2, w3, b3, out, npts);
}

// Round 3
// 1216.006 us; speedup vs baseline: 1.2585x; 1.2585x over previous
//
#include <hip/hip_runtime.h>

// Instant-NGP 2D hashgrid (L=16, T=2^20, F=2, N_MIN=16, b=2) + MLP 32->128->128->3.
// R3: depth-1/2 single-buffer pipeline. R2's double-buffer Pref pushed VGPR
// demand ~210 > the (256,3) cap of ~168 -> compiler spilled pipeline state to
// scratch (WRITE_SIZE 12MB -> 1.75GB). Fix: consume tile t's gathers into xb
// FIRST, then reissue tile t+1's gathers into the SAME Pref registers, then do
// the long MLP compute. One in-flight buffer (~40 VGPRs), total ~150 < 168.
// Barriers stay removed: hbuf is per-wave; w2T/biases read-only after init.
//
// GEMM formulation: h^T = W^T x^T  (rows m = neurons, cols n = points).
//   mfma_f32_16x16x32_bf16 layouts (HW-verified per guide):
//     A[m][k]: m = lane&15, k = (lane>>4)*8 + j   (8 bf16 / lane)
//     B[k][n]: n = lane&15, k = (lane>>4)*8 + j
//     D[m][n]: n = lane&15, m = (lane>>4)*4 + r   (4 f32 / lane)
// Lane (quad, lo) encodes point lo at levels 4*quad .. 4*quad+3 == features
// k = quad*8 .. quad*8+7  ->  exactly its layer-1 B-fragment. No shuffle.

#define T_SIZE  (1u << 20)
#define HASH_Y  2654435761u

typedef __bf16 bf16x8 __attribute__((ext_vector_type(8)));
typedef float f32x4 __attribute__((ext_vector_type(4)));
typedef unsigned short u16x8 __attribute__((ext_vector_type(8)));
typedef unsigned short u16x4 __attribute__((ext_vector_type(4)));

static __device__ __forceinline__ unsigned short f2bf(float f) {
    union { float f; unsigned u; } v; v.f = f;
    unsigned u = v.u;
    u += 0x7fffu + ((u >> 16) & 1u);   // round-to-nearest-even
    return (unsigned short)(u >> 16);
}

static __device__ __forceinline__ f32x4 mfma16(u16x8 a, u16x8 b, f32x4 c) {
    return __builtin_amdgcn_mfma_f32_16x16x32_bf16(
        __builtin_bit_cast(bf16x8, a), __builtin_bit_cast(bf16x8, b), c, 0, 0, 0);
}

// Per-lane in-flight gather state for one 16-point tile (4 levels x 4 corners).
struct Pref {
    float2 f[16];
    float wx[4], wy[4];
};

// Issue the 16 table gathers for point `pt`, levels 4*quad..4*quad+3.
static __device__ __forceinline__ void issue_gathers(
    Pref& P, const float2* __restrict__ uv2, const float2* __restrict__ t2base,
    int pt, int quad)
{
    float2 p = uv2[pt];
#pragma unroll
    for (int i = 0; i < 4; ++i) {
        int lvl = (quad << 2) + i;
        unsigned res = 16u << lvl;
        float px = p.x * (float)res, py = p.y * (float)res;
        float fx = floorf(px), fy = floorf(py);
        P.wx[i] = px - fx;
        P.wy[i] = py - fy;
        unsigned cx = (unsigned)fx, cy = (unsigned)fy;
        unsigned rp1 = res + 1u;
        unsigned hy0 = cy * HASH_Y, hy1 = (cy + 1u) * HASH_Y;
        const unsigned mask = T_SIZE - 1u;
        bool dense = lvl < 6;                  // (res+1)^2 <= T  <=>  lvl <= 5
        unsigned i00 = dense ? (cx + cy * rp1)              : ((cx ^ hy0) & mask);
        unsigned i01 = dense ? (cx + (cy + 1u) * rp1)       : ((cx ^ hy1) & mask);
        unsigned i10 = dense ? (cx + 1u + cy * rp1)         : (((cx + 1u) ^ hy0) & mask);
        unsigned i11 = dense ? (cx + 1u + (cy + 1u) * rp1)  : (((cx + 1u) ^ hy1) & mask);
        const float2* t2 = t2base + (size_t)lvl * T_SIZE;
        P.f[4 * i + 0] = t2[i00];
        P.f[4 * i + 1] = t2[i01];
        P.f[4 * i + 2] = t2[i10];
        P.f[4 * i + 3] = t2[i11];
    }
}

// Bilinear interp: consumes P (this is where the vmcnt wait lands).
static __device__ __forceinline__ u16x8 interp_tile(const Pref& P) {
    u16x8 xb;
#pragma unroll
    for (int i = 0; i < 4; ++i) {
        float wx = P.wx[i], wy = P.wy[i];
        float w00 = (1.f - wx) * (1.f - wy);
        float w01 = (1.f - wx) * wy;
        float w10 = wx * (1.f - wy);
        float w11 = wx * wy;
        float2 f00 = P.f[4 * i + 0], f01 = P.f[4 * i + 1];
        float2 f10 = P.f[4 * i + 2], f11 = P.f[4 * i + 3];
        float g0 = w00 * f00.x + w01 * f01.x + w10 * f10.x + w11 * f11.x;
        float g1 = w00 * f00.y + w01 * f01.y + w10 * f10.y + w11 * f11.y;
        xb[2 * i]     = f2bf(g0);
        xb[2 * i + 1] = f2bf(g1);
    }
    return xb;
}

// Layer1 -> LDS -> layer2 -> LDS -> layer3 -> sigmoid -> out.
static __device__ __forceinline__ void mlp_tile(
    u16x8 xb, int pt, int quad, int lanelo,
    unsigned short* __restrict__ hp, const unsigned short* __restrict__ w2T,
    const u16x8* __restrict__ a1, const u16x8* __restrict__ a3,
    const float* __restrict__ b1s, const float* __restrict__ b2s,
    const float* __restrict__ b3v, float* __restrict__ out)
{
    f32x4 z = {0.f, 0.f, 0.f, 0.f};
    // ---- layer 1: 8 MFMAs, K=32 ----
    f32x4 d[8];
#pragma unroll
    for (int mt = 0; mt < 8; ++mt) d[mt] = mfma16(a1[mt], xb, z);
#pragma unroll
    for (int mt = 0; mt < 8; ++mt) {
        u16x4 pk;
#pragma unroll
        for (int r = 0; r < 4; ++r) {
            float hv = d[mt][r] + b1s[mt * 16 + quad * 4 + r];
            pk[r] = f2bf(fmaxf(hv, 0.f));
        }
        *(u16x4*)(hp + mt * 16 + quad * 4) = pk;
    }
    // ---- layer 2: K=128 in 4 steps x 8 m-tiles (wave-internal LDS, DS in-order) ----
    f32x4 e[8];
#pragma unroll
    for (int mt = 0; mt < 8; ++mt) e[mt] = z;
#pragma unroll
    for (int ks = 0; ks < 4; ++ks) {
        u16x8 bb = *(const u16x8*)(hp + ks * 32 + quad * 8);
#pragma unroll
        for (int mt = 0; mt < 8; ++mt) {
            u16x8 aa = *(const u16x8*)(w2T + (mt * 16 + lanelo) * 136 + ks * 32 + quad * 8);
            e[mt] = mfma16(aa, bb, e[mt]);
        }
    }
#pragma unroll
    for (int mt = 0; mt < 8; ++mt) {
        u16x4 pk;
#pragma unroll
        for (int r = 0; r < 4; ++r) {
            float hv = e[mt][r] + b2s[mt * 16 + quad * 4 + r];
            pk[r] = f2bf(fmaxf(hv, 0.f));
        }
        *(u16x4*)(hp + mt * 16 + quad * 4) = pk;
    }
    // ---- layer 3: 4 MFMAs, rows 0..2 = RGB logits ----
    f32x4 o3 = z;
#pragma unroll
    for (int ks = 0; ks < 4; ++ks) {
        u16x8 bb = *(const u16x8*)(hp + ks * 32 + quad * 8);
        o3 = mfma16(a3[ks], bb, o3);
    }
    if (quad == 0) {   // D rows 0..2 live in quad 0, r=0..2
        float* op = out + (size_t)pt * 3;
#pragma unroll
        for (int r = 0; r < 3; ++r) {
            float lv = o3[r] + b3v[r];
            op[r] = 1.f / (1.f + expf(-lv));
        }
    }
}

// LDS: w2T[out 128][in 136 pad] bf16 (34816 B) + h[4 waves][16 pts][136 pad]
// (17408 B) + biases (1024 B) = 53248 B -> 3 blocks/CU (LDS-bound).
// VGPR budget: (256,3) caps ~168; demand ~150 (a1 32 + a3 16 + Pref 40 +
// acc 32 + misc) -> no spill.
__global__ __launch_bounds__(256, 3)
void fused_ngp_mlp(const float* __restrict__ uv, const float* __restrict__ tables,
                   const float* __restrict__ w1, const float* __restrict__ b1,
                   const float* __restrict__ w2, const float* __restrict__ b2,
                   const float* __restrict__ w3, const float* __restrict__ b3,
                   float* __restrict__ out, int npts)
{
    __shared__ __align__(16) unsigned short w2T[128 * 136];
    __shared__ __align__(16) unsigned short hbuf[4 * 16 * 136];
    __shared__ float b1s[128], b2s[128];

    const int tid = threadIdx.x;
    for (int e2 = tid; e2 < 128 * 128; e2 += 256) {     // w2 is [in][out]; store w2T[out][in]
        int i = e2 >> 7, o = e2 & 127;
        w2T[o * 136 + i] = f2bf(w2[e2]);
    }
    if (tid < 128) { b1s[tid] = b1[tid]; b2s[tid] = b2[tid]; }
    __syncthreads();   // only barrier: w2T/bias init. hbuf is per-wave after this.

    const int lane = tid & 63;
    const int wv = tid >> 6;
    const int lanelo = lane & 15;
    const int quad = lane >> 4;

    // Register-resident A-fragments: layer 1 (w1^T [128x32]) and layer 3 (w3^T [3x128]).
    u16x8 a1[8];
#pragma unroll
    for (int mt = 0; mt < 8; ++mt)
#pragma unroll
        for (int j = 0; j < 8; ++j)
            a1[mt][j] = f2bf(w1[(quad * 8 + j) * 128 + mt * 16 + lanelo]);  // w1[k][m]

    u16x8 a3[4];
#pragma unroll
    for (int ks = 0; ks < 4; ++ks)
#pragma unroll
        for (int j = 0; j < 8; ++j) {
            int k = ks * 32 + quad * 8 + j;
            a3[ks][j] = (lanelo < 3) ? f2bf(w3[k * 3 + lanelo]) : (unsigned short)0;  // w3[k][m]
        }

    float b3v[3] = {b3[0], b3[1], b3[2]};

    const int NT = npts >> 4;                 // 16-point tiles
    const int nwaves = gridDim.x * 4;
    const int gwave = blockIdx.x * 4 + wv;

    unsigned short* hp = hbuf + (wv * 16 + lanelo) * 136;   // this lane's point-row
    const float2* t2base = (const float2*)tables;
    const float2* uv2 = (const float2*)uv;

    // ---- depth-1/2 pipelined persistent loop (single Pref buffer) ----
    int tile = gwave;
    if (tile >= NT) return;
    Pref P;
    issue_gathers(P, uv2, t2base, (tile << 4) + lanelo, quad);
    for (;;) {
        int pt = (tile << 4) + lanelo;
        u16x8 xb = interp_tile(P);            // waits on this tile's gathers, frees P.f
        int nxt = tile + nwaves;
        bool more = nxt < NT;
        if (more)
            issue_gathers(P, uv2, t2base, (nxt << 4) + lanelo, quad);  // overlaps MLP below
        mlp_tile(xb, pt, quad, lanelo, hp, w2T, a1, a3, b1s, b2s, b3v, out);
        if (!more) return;
        tile = nxt;
    }
}

extern "C" void kernel_launch(void* const* d_in, const int* in_sizes, int n_in,
                              void* d_out, int out_size, void* d_ws, size_t ws_size,
                              hipStream_t stream) {
    const float* uv     = (const float*)d_in[0];
    const float* tables = (const float*)d_in[1];
    const float* w1     = (const float*)d_in[2];
    const float* b1     = (const float*)d_in[3];
    const float* w2     = (const float*)d_in[4];
    const float* b2     = (const float*)d_in[5];
    const float* w3     = (const float*)d_in[6];
    const float* b3     = (const float*)d_in[7];
    float* out = (float*)d_out;
    int npts = in_sizes[0] / 2;          // uv is [N,2]
    // 2048 blocks x 4 waves = 8192 wave-slots; 65536 tiles -> 8 tiles/wave, exact.
    hipLaunchKernelGGL(fused_ngp_mlp, dim3(2048), dim3(256), 0, stream,
                       uv, tables, w1, b1, w2, b2, w3, b3, out, npts);
}